// Round 5
// baseline (264.639 us; speedup 1.0000x reference)
//
#include <hip/hip_runtime.h>
#include <cstdint>

typedef __attribute__((ext_vector_type(8))) short short8v;  // 8 bf16 (4 VGPR)
typedef __attribute__((ext_vector_type(4))) float f32x4;

#define KCODES 2048
#define CDIM 256
#define HWN 1024
#define MROWS 32768
#define MARGIN 1.0f
#define CAP (1 << 19)
#define LCAP 2048

__device__ __forceinline__ unsigned short f2bf(float f) {
  unsigned u = __float_as_uint(f);
  unsigned r = (u + 0x7fffu + ((u >> 16) & 1u)) >> 16;   // RNE
  return (unsigned short)r;
}

// ---------------- transpose: X[b,c,n] -> Xrow f32 [row][c] + Xbf bf16 -------
// also folds: rkey = +inf init, count = 0
__global__ __launch_bounds__(256) void transpose_kernel(
    const float* __restrict__ X, float* __restrict__ Xrow,
    unsigned short* __restrict__ Xbf,
    unsigned long long* __restrict__ rkey, int* __restrict__ count) {
  __shared__ float t[64][65];
  int bid = blockIdx.x;
  int gid = bid * 256 + threadIdx.x;
  if (gid < MROWS) rkey[gid] = ~0ULL;
  if (gid == 0) *count = 0;
  int b = bid >> 6, rem = bid & 63;
  int c0 = (rem >> 4) * 64, n0 = (rem & 15) * 64;
  int g = threadIdx.x >> 6, lane = threadIdx.x & 63;
  const float* xb = X + ((size_t)b * CDIM) * HWN;
  #pragma unroll
  for (int i = 0; i < 16; ++i) {
    int c = g * 16 + i;
    t[c][lane] = xb[(size_t)(c0 + c) * HWN + n0 + lane];   // coalesced read
  }
  __syncthreads();
  #pragma unroll
  for (int i = 0; i < 16; ++i) {
    int nn = g * 16 + i;
    float v = t[lane][nn];                                 // 2-way (free)
    size_t row = (size_t)b * HWN + n0 + nn;
    Xrow[row * CDIM + c0 + lane] = v;                      // coalesced write
    Xbf [row * CDIM + c0 + lane] = f2bf(v);
  }
}

// ---------------- e2[k] = sum E[k][c]^2 (fp32 exact) + Ebf bf16 -------------
__global__ __launch_bounds__(256) void e2_kernel(const float* __restrict__ E,
                                                 float* __restrict__ e2,
                                                 unsigned short* __restrict__ Ebf) {
  int gt = blockIdx.x * 256 + threadIdx.x;
  int k = gt >> 6, lane = threadIdx.x & 63;
  const float4 v = reinterpret_cast<const float4*>(E + (size_t)k * CDIM)[lane];
  unsigned lo = (unsigned)f2bf(v.x) | ((unsigned)f2bf(v.y) << 16);
  unsigned hi = (unsigned)f2bf(v.z) | ((unsigned)f2bf(v.w) << 16);
  uint2 p; p.x = lo; p.y = hi;
  *reinterpret_cast<uint2*>(Ebf + (size_t)k * CDIM + 4 * lane) = p;
  float s = v.x*v.x + v.y*v.y + v.z*v.z + v.w*v.w;
  #pragma unroll
  for (int off = 32; off > 0; off >>= 1) s += __shfl_down(s, off);
  if (lane == 0) e2[k] = s;
}

// ---------------- MFMA approx-distance + candidate collection ---------------
// 128 rows x 1024 codes per block; 16 chunks of 64 codes, double-buffered LDS.
// Staging: global_load_lds (no VGPR round-trip) with pre-swizzled per-lane
// global source so the linear LDS write realizes LDS[r*512+p]=global(r,p^sw),
// sw=(r&7)<<4 -- identical mapping to the (verified) reg-staged r3/r4 writes.
// Pipeline: STAGE(t+1) -> vmcnt(8) -> s_barrier -> compute(t) -> s_barrier.
__global__ __launch_bounds__(256, 2) void cand_kernel(
    const unsigned short* __restrict__ Xbf,
    const unsigned short* __restrict__ Ebf,
    const float* __restrict__ e2,
    unsigned* __restrict__ list, int* __restrict__ count)
{
  __shared__ unsigned short elds[2][16384];   // 2 x 32 KB
  __shared__ float e2l[1024];                 // 4 KB
  __shared__ unsigned cbuf[LCAP];             // 8 KB
  __shared__ int lcount;
  __shared__ int gbase;

  const int tid = threadIdx.x;
  const int wave = tid >> 6, lane = tid & 63;
  const int l15 = lane & 15, l4 = lane >> 4;
  const int rowblk = blockIdx.x >> 1;
  const int nhalf = blockIdx.x & 1;
  const int row0 = rowblk * 128 + wave * 32;
  const int code0 = nhalf * 1024;

  if (tid == 0) lcount = 0;

  // e2 for this code-half -> LDS
  {
    float4 ev = *reinterpret_cast<const float4*>(e2 + code0 + tid * 4);
    *reinterpret_cast<float4*>(&e2l[tid * 4]) = ev;
  }

  // A fragments: 32 rows x 256 ch bf16 resident in registers (64 VGPR)
  short8v af[2][8];
  #pragma unroll
  for (int mt = 0; mt < 2; ++mt)
    #pragma unroll
    for (int kt = 0; kt < 8; ++kt)
      af[mt][kt] = *reinterpret_cast<const short8v*>(
          Xbf + (size_t)(row0 + mt * 16 + l15) * CDIM + kt * 32 + l4 * 8);

  // per-lane pre-swizzled staging source base (invariant across chunks/issues)
  const int r0 = 2 * wave + (lane >> 5);                  // 0..7
  const int soff = r0 * 512 + (((lane & 31) * 16) ^ (r0 << 4));
  const char* srcbase = (const char*)Ebf + (size_t)code0 * 512 + soff;
  char* dst0 = (char*)&elds[0][0] + wave * 1024;
  char* dst1 = (char*)&elds[1][0] + wave * 1024;

  // issue chunk 0 -> buf0
  #pragma unroll
  for (int j = 0; j < 8; ++j)
    __builtin_amdgcn_global_load_lds(
        (const __attribute__((address_space(1))) unsigned int*)(srcbase + j * 4096),
        (__attribute__((address_space(3))) unsigned int*)(dst0 + j * 4096), 16, 0, 0);

  float runmin0[4], runmin1[4];
  #pragma unroll
  for (int r = 0; r < 4; ++r) { runmin0[r] = 3.4e38f; runmin1[r] = 3.4e38f; }

  __syncthreads();   // e2l + lcount visible; drains chunk-0 staging (once)

  for (int chunk = 0; chunk < 16; ++chunk) {
    const int cur = chunk & 1;
    if (chunk < 15) {   // stage chunk+1 into the other buffer
      const char* s = srcbase + (size_t)(chunk + 1) * 32768;
      char* d = cur ? dst0 : dst1;
      #pragma unroll
      for (int j = 0; j < 8; ++j)
        __builtin_amdgcn_global_load_lds(
            (const __attribute__((address_space(1))) unsigned int*)(s + j * 4096),
            (__attribute__((address_space(3))) unsigned int*)(d + j * 4096), 16, 0, 0);
      asm volatile("s_waitcnt vmcnt(8)" ::: "memory");   // chunk t's 8 retired
    } else {
      asm volatile("s_waitcnt vmcnt(0)" ::: "memory");
    }
    __builtin_amdgcn_s_barrier();          // all waves: buf[cur] fully written
    asm volatile("" ::: "memory");         // fence: no LDS reads hoisted above

    const char* lbase = (const char*)&elds[cur][0];
    #pragma unroll
    for (int nsub = 0; nsub < 4; ++nsub) {
      f32x4 a0 = {0.f, 0.f, 0.f, 0.f}, a1 = {0.f, 0.f, 0.f, 0.f};
      const int rn = nsub * 16 + l15;
      const char* lb = lbase + rn * 512;
      const int sw = (rn & 7) << 4;
      #pragma unroll
      for (int kt = 0; kt < 8; ++kt) {
        short8v bf = *reinterpret_cast<const short8v*>(lb + ((kt * 64 + l4 * 16) ^ sw));
        a0 = __builtin_amdgcn_mfma_f32_16x16x32_bf16(af[0][kt], bf, a0, 0, 0, 0);
        a1 = __builtin_amdgcn_mfma_f32_16x16x32_bf16(af[1][kt], bf, a1, 0, 0, 0);
      }
      const float e2v = e2l[(chunk << 6) + (nsub << 4) + l15];
      float s0r[4], s1r[4], m0[4], m1[4];
      #pragma unroll
      for (int r = 0; r < 4; ++r) {
        s0r[r] = fmaf(-2.f, a0[r], e2v);  m0[r] = s0r[r];
        s1r[r] = fmaf(-2.f, a1[r], e2v);  m1[r] = s1r[r];
      }
      #pragma unroll
      for (int off = 1; off < 16; off <<= 1)
        #pragma unroll
        for (int r = 0; r < 4; ++r) {
          m0[r] = fminf(m0[r], __shfl_xor(m0[r], off));
          m1[r] = fminf(m1[r], __shfl_xor(m1[r], off));
        }
      const int code = code0 + (chunk << 6) + (nsub << 4) + l15;
      #pragma unroll
      for (int r = 0; r < 4; ++r) {
        float ub0 = fminf(runmin0[r], m0[r]); runmin0[r] = ub0;
        float ub1 = fminf(runmin1[r], m1[r]); runmin1[r] = ub1;
        if (s0r[r] <= ub0 + MARGIN) {
          unsigned entry = ((unsigned)(row0 + 4 * l4 + r) << 11) | (unsigned)code;
          int pos = atomicAdd(&lcount, 1);
          if (pos < LCAP) cbuf[pos] = entry;
          else { int gp = atomicAdd(count, 1); if (gp < CAP) list[gp] = entry; }
        }
        if (s1r[r] <= ub1 + MARGIN) {
          unsigned entry = ((unsigned)(row0 + 16 + 4 * l4 + r) << 11) | (unsigned)code;
          int pos = atomicAdd(&lcount, 1);
          if (pos < LCAP) cbuf[pos] = entry;
          else { int gp = atomicAdd(count, 1); if (gp < CAP) list[gp] = entry; }
        }
      }
    }
    __builtin_amdgcn_s_barrier();   // all waves done reading buf[cur]
    asm volatile("" ::: "memory");
  }

  // ---- publish the block's candidate list: ONE global atomic per block ----
  __syncthreads();
  int lc = lcount; if (lc > LCAP) lc = LCAP;
  if (tid == 0) gbase = atomicAdd(count, lc);
  __syncthreads();
  int gb = gbase;
  for (int i = tid; i < lc; i += 256) {
    int gp = gb + i;
    if (gp < CAP) list[gp] = cbuf[i];
  }
}

// ---------------- exact fp32 refine of candidates ---------------------------
__global__ __launch_bounds__(256) void refine_kernel(
    const float* __restrict__ Xrow, const float* __restrict__ E,
    const float* __restrict__ e2, const unsigned* __restrict__ list,
    const int* __restrict__ count, unsigned long long* __restrict__ rkey)
{
  const int lane = threadIdx.x & 63;
  const int wid = (blockIdx.x * 256 + threadIdx.x) >> 6;
  int cnt = *count; if (cnt > CAP) cnt = CAP;
  for (int i = wid; i < cnt; i += 4096) {
    unsigned p = list[i];
    int row = p >> 11, k = p & 2047;
    const float4 xv = reinterpret_cast<const float4*>(Xrow + (size_t)row * CDIM)[lane];
    const float4 ev = reinterpret_cast<const float4*>(E + (size_t)k * CDIM)[lane];
    float d = fmaf(xv.x, ev.x, fmaf(xv.y, ev.y, fmaf(xv.z, ev.z, xv.w * ev.w)));
    #pragma unroll
    for (int off = 32; off > 0; off >>= 1) d += __shfl_xor(d, off);
    if (lane == 0) {
      float s = fmaf(-2.f, d, e2[k]);
      unsigned u = __float_as_uint(s);
      u = (u & 0x80000000u) ? ~u : (u | 0x80000000u);   // monotone encode
      unsigned long long key = ((unsigned long long)u << 32) | (unsigned)k;
      atomicMin(&rkey[row], key);   // order-independent -> deterministic
    }
  }
}

// ---------------- gather codebook rows + MSE partials (reads rkey) ----------
__global__ __launch_bounds__(256) void out_kernel(
    const float* __restrict__ X, const float* __restrict__ E,
    const unsigned long long* __restrict__ rkey, float* __restrict__ out,
    float* __restrict__ partial)
{
  __shared__ float warpsum[4];
  size_t t = (size_t)blockIdx.x * 256 + threadIdx.x;
  size_t base = t * 8;
  float lsum = 0.f;
  #pragma unroll
  for (int g = 0; g < 2; ++g) {
    size_t e0 = base + (size_t)g * 4;
    int b = (int)(e0 >> 18);
    int c = (int)((e0 >> 10) & 255);
    int n = (int)(e0 & 1023);
    const unsigned long long* kp = rkey + b * HWN + n;
    int i0 = (int)(kp[0] & 2047ULL), i1 = (int)(kp[1] & 2047ULL);
    int i2 = (int)(kp[2] & 2047ULL), i3 = (int)(kp[3] & 2047ULL);
    float4 q;
    q.x = E[(size_t)i0 * CDIM + c];
    q.y = E[(size_t)i1 * CDIM + c];
    q.z = E[(size_t)i2 * CDIM + c];
    q.w = E[(size_t)i3 * CDIM + c];
    const float4 xv = *reinterpret_cast<const float4*>(X + e0);
    *reinterpret_cast<float4*>(out + e0) = q;
    float dx = xv.x - q.x, dy = xv.y - q.y, dz = xv.z - q.z, dw = xv.w - q.w;
    lsum += dx*dx + dy*dy + dz*dz + dw*dw;
  }
  #pragma unroll
  for (int off = 32; off > 0; off >>= 1) lsum += __shfl_down(lsum, off);
  int lane = threadIdx.x & 63, wv = threadIdx.x >> 6;
  if (lane == 0) warpsum[wv] = lsum;
  __syncthreads();
  if (threadIdx.x == 0)
    partial[blockIdx.x] = warpsum[0] + warpsum[1] + warpsum[2] + warpsum[3];
}

// ---------------- deterministic final loss reduce ---------------------------
__global__ __launch_bounds__(256) void loss_kernel(const float* __restrict__ partial,
                                                   float* __restrict__ out_loss) {
  __shared__ double sd[256];
  double s = 0.0;
  for (int i = threadIdx.x; i < 4096; i += 256) s += (double)partial[i];
  sd[threadIdx.x] = s;
  __syncthreads();
  if (threadIdx.x == 0) {
    double tot = 0.0;
    for (int i = 0; i < 256; ++i) tot += sd[i];
    out_loss[0] = (float)(tot / 8388608.0);
  }
}

extern "C" void kernel_launch(void* const* d_in, const int* in_sizes, int n_in,
                              void* d_out, int out_size, void* d_ws, size_t ws_size,
                              hipStream_t stream) {
  const float* X = (const float*)d_in[0];   // [32,256,32,32] fp32
  const float* E = (const float*)d_in[1];   // [2048,256] fp32
  float* out = (float*)d_out;               // 8388608 quantized + 1 loss
  char* ws = (char*)d_ws;

  float*              e2    = (float*)(ws + 0);                 // 8 KB
  unsigned short*     Ebf   = (unsigned short*)(ws + 8192);     // 1 MB
  unsigned short*     Xbf   = (unsigned short*)(ws + 1056768);  // 16 MB
  unsigned long long* rkey  = (unsigned long long*)(ws + 17833984); // 256 KB
  int*                count = (int*)(ws + 18096128);            // 256 B
  unsigned*           list  = (unsigned*)(ws + 18227456);       // 2 MB
  float*              partial = (float*)(ws + 20324608);        // 16 KB
  float* Xrow = out;   // fp32 row-major X stashed in d_out; overwritten by out_kernel

  transpose_kernel<<<2048, 256, 0, stream>>>(X, Xrow, Xbf, rkey, count);
  e2_kernel       <<<512,  256, 0, stream>>>(E, e2, Ebf);
  cand_kernel     <<<512,  256, 0, stream>>>(Xbf, Ebf, e2, list, count);
  refine_kernel   <<<1024, 256, 0, stream>>>(Xrow, E, e2, list, count, rkey);
  out_kernel      <<<4096, 256, 0, stream>>>(X, E, rkey, out, partial);
  loss_kernel     <<<1,    256, 0, stream>>>(partial, out + 8388608);
}

// Round 6
// 160.965 us; speedup vs baseline: 1.6441x; 1.6441x over previous
//
#include <hip/hip_runtime.h>
#include <cstdint>

typedef __attribute__((ext_vector_type(8))) short short8v;  // 8 bf16 (4 VGPR)
typedef __attribute__((ext_vector_type(4))) float f32x4;

#define KCODES 2048
#define CDIM 256
#define HWN 1024
#define MROWS 32768
#define MARGIN 1.0f
#define CAP (1 << 19)
#define LCAP 1024

__device__ __forceinline__ unsigned short f2bf(float f) {
  unsigned u = __float_as_uint(f);
  unsigned r = (u + 0x7fffu + ((u >> 16) & 1u)) >> 16;   // RNE
  return (unsigned short)r;
}

// 16-lane idempotent min-reduce steps via DPP (pure VALU, no LDS pipe):
// 0xB1 quad_perm[1,0,3,2] (xor1), 0x4E quad_perm[2,3,0,1] (xor2),
// 0x141 row_half_mirror (i<->7-i), 0x140 row_mirror (i<->15-i).
#define FMIN_DPP(v, CTRL) \
  fminf(v, __int_as_float(__builtin_amdgcn_update_dpp( \
      0, __float_as_int(v), CTRL, 0xf, 0xf, true)))

// ---------------- prep: transpose + inits (blocks <2048) | e2/Ebf (rest) ----
__global__ __launch_bounds__(256) void prep_kernel(
    const float* __restrict__ X, float* __restrict__ Xrow,
    unsigned short* __restrict__ Xbf,
    unsigned long long* __restrict__ rkey, int* __restrict__ count,
    const float* __restrict__ E, float* __restrict__ e2,
    unsigned short* __restrict__ Ebf) {
  __shared__ float t[64][65];
  int bid = blockIdx.x;
  if (bid >= 2048) {          // ---- e2 role: one wave per code ----
    int gt = (bid - 2048) * 256 + threadIdx.x;
    int k = gt >> 6, lane = threadIdx.x & 63;
    const float4 v = reinterpret_cast<const float4*>(E + (size_t)k * CDIM)[lane];
    unsigned lo = (unsigned)f2bf(v.x) | ((unsigned)f2bf(v.y) << 16);
    unsigned hi = (unsigned)f2bf(v.z) | ((unsigned)f2bf(v.w) << 16);
    uint2 p; p.x = lo; p.y = hi;
    *reinterpret_cast<uint2*>(Ebf + (size_t)k * CDIM + 4 * lane) = p;
    float s = v.x*v.x + v.y*v.y + v.z*v.z + v.w*v.w;
    #pragma unroll
    for (int off = 32; off > 0; off >>= 1) s += __shfl_down(s, off);
    if (lane == 0) e2[k] = s;
    return;
  }
  // ---- transpose role ----
  int gid = bid * 256 + threadIdx.x;
  if (gid < MROWS) rkey[gid] = ~0ULL;
  if (gid == 0) *count = 0;
  int b = bid >> 6, rem = bid & 63;
  int c0 = (rem >> 4) * 64, n0 = (rem & 15) * 64;
  int g = threadIdx.x >> 6, lane = threadIdx.x & 63;
  const float* xb = X + ((size_t)b * CDIM) * HWN;
  #pragma unroll
  for (int i = 0; i < 16; ++i) {
    int c = g * 16 + i;
    t[c][lane] = xb[(size_t)(c0 + c) * HWN + n0 + lane];   // coalesced read
  }
  __syncthreads();
  #pragma unroll
  for (int i = 0; i < 16; ++i) {
    int nn = g * 16 + i;
    float v = t[lane][nn];                                 // 2-way (free)
    size_t row = (size_t)b * HWN + n0 + nn;
    Xrow[row * CDIM + c0 + lane] = v;                      // coalesced write
    Xbf [row * CDIM + c0 + lane] = f2bf(v);
  }
}

// ---------------- MFMA approx-distance, TWO-PASS candidate collection -------
// 128 rows x 1024 codes per block; 32 iterations = 2 passes x 16 chunks of 64
// codes, double-buffered LDS staged via global_load_lds (pre-swizzled source).
// Pass 1 (i<16): MFMA + per-(lane,r) register min only (no cross-lane ops).
// Boundary (i==15): 16-lane DPP min-reduce -> exact bf16 row min -> thr.
// Pass 2 (i>=16): identical MFMA replay (bit-exact), insert s <= thr.
__global__ __launch_bounds__(256, 2) void cand_kernel(
    const unsigned short* __restrict__ Xbf,
    const unsigned short* __restrict__ Ebf,
    const float* __restrict__ e2,
    unsigned* __restrict__ list, int* __restrict__ count)
{
  __shared__ unsigned short elds[2][16384];   // 2 x 32 KB
  __shared__ float e2l[1024];                 // 4 KB
  __shared__ unsigned cbuf[LCAP];             // 4 KB
  __shared__ int lcount;
  __shared__ int gbase;

  const int tid = threadIdx.x;
  const int wave = tid >> 6, lane = tid & 63;
  const int l15 = lane & 15, l4 = lane >> 4;
  const int rowblk = blockIdx.x >> 1;
  const int nhalf = blockIdx.x & 1;
  const int row0 = rowblk * 128 + wave * 32;
  const int code0 = nhalf * 1024;

  if (tid == 0) lcount = 0;

  // e2 for this code-half -> LDS
  {
    float4 ev = *reinterpret_cast<const float4*>(e2 + code0 + tid * 4);
    *reinterpret_cast<float4*>(&e2l[tid * 4]) = ev;
  }

  // A fragments: 32 rows x 256 ch bf16 resident in registers (64 VGPR)
  short8v af[2][8];
  #pragma unroll
  for (int mt = 0; mt < 2; ++mt)
    #pragma unroll
    for (int kt = 0; kt < 8; ++kt)
      af[mt][kt] = *reinterpret_cast<const short8v*>(
          Xbf + (size_t)(row0 + mt * 16 + l15) * CDIM + kt * 32 + l4 * 8);

  // per-lane pre-swizzled staging source base (chunk-cyclic, same both passes)
  const int r0 = 2 * wave + (lane >> 5);                  // 0..7
  const int soff = r0 * 512 + (((lane & 31) * 16) ^ (r0 << 4));
  const char* srcbase = (const char*)Ebf + (size_t)code0 * 512 + soff;
  char* dst0 = (char*)&elds[0][0] + wave * 1024;
  char* dst1 = (char*)&elds[1][0] + wave * 1024;

  // issue chunk 0 -> buf0
  #pragma unroll
  for (int j = 0; j < 8; ++j)
    __builtin_amdgcn_global_load_lds(
        (const __attribute__((address_space(1))) unsigned int*)(srcbase + j * 4096),
        (__attribute__((address_space(3))) unsigned int*)(dst0 + j * 4096), 16, 0, 0);

  float m0[4], m1[4], thr0[4], thr1[4];
  #pragma unroll
  for (int r = 0; r < 4; ++r) { m0[r] = 3.4e38f; m1[r] = 3.4e38f; }

  __syncthreads();   // e2l + lcount visible

  #pragma unroll 1
  for (int i = 0; i < 32; ++i) {
    const int cur = i & 1;
    if (i < 31) {   // stage next chunk (cyclic) into the other buffer
      const char* s = srcbase + (size_t)((i + 1) & 15) * 32768;
      char* d = cur ? dst0 : dst1;
      #pragma unroll
      for (int j = 0; j < 8; ++j)
        __builtin_amdgcn_global_load_lds(
            (const __attribute__((address_space(1))) unsigned int*)(s + j * 4096),
            (__attribute__((address_space(3))) unsigned int*)(d + j * 4096), 16, 0, 0);
      asm volatile("s_waitcnt vmcnt(8)" ::: "memory");   // this chunk's 8 done
    } else {
      asm volatile("s_waitcnt vmcnt(0)" ::: "memory");
    }
    __builtin_amdgcn_s_barrier();          // all waves: buf[cur] fully written
    asm volatile("" ::: "memory");

    const char* lbase = (const char*)&elds[cur][0];
    const int cc6 = (i & 15) << 6;
    #pragma unroll
    for (int nsub = 0; nsub < 4; ++nsub) {
      f32x4 a0 = {0.f, 0.f, 0.f, 0.f}, a1 = {0.f, 0.f, 0.f, 0.f};
      const int rn = nsub * 16 + l15;
      const char* lb = lbase + rn * 512;
      const int sw = (rn & 7) << 4;
      #pragma unroll
      for (int kt = 0; kt < 8; ++kt) {
        short8v bf = *reinterpret_cast<const short8v*>(lb + ((kt * 64 + l4 * 16) ^ sw));
        a0 = __builtin_amdgcn_mfma_f32_16x16x32_bf16(af[0][kt], bf, a0, 0, 0, 0);
        a1 = __builtin_amdgcn_mfma_f32_16x16x32_bf16(af[1][kt], bf, a1, 0, 0, 0);
      }
      const float e2v = e2l[cc6 + (nsub << 4) + l15];
      if (i < 16) {          // pass 1: register min only
        #pragma unroll
        for (int r = 0; r < 4; ++r) {
          m0[r] = fminf(m0[r], fmaf(-2.f, a0[r], e2v));
          m1[r] = fminf(m1[r], fmaf(-2.f, a1[r], e2v));
        }
      } else {               // pass 2: bit-exact replay, rare inserts
        const int code = code0 + cc6 + (nsub << 4) + l15;
        #pragma unroll
        for (int r = 0; r < 4; ++r) {
          float s0r = fmaf(-2.f, a0[r], e2v);
          float s1r = fmaf(-2.f, a1[r], e2v);
          if (s0r <= thr0[r]) {
            unsigned entry = ((unsigned)(row0 + 4 * l4 + r) << 11) | (unsigned)code;
            int pos = atomicAdd(&lcount, 1);
            if (pos < LCAP) cbuf[pos] = entry;
            else { int gp = atomicAdd(count, 1); if (gp < CAP) list[gp] = entry; }
          }
          if (s1r <= thr1[r]) {
            unsigned entry = ((unsigned)(row0 + 16 + 4 * l4 + r) << 11) | (unsigned)code;
            int pos = atomicAdd(&lcount, 1);
            if (pos < LCAP) cbuf[pos] = entry;
            else { int gp = atomicAdd(count, 1); if (gp < CAP) list[gp] = entry; }
          }
        }
      }
    }
    if (i == 15) {   // pass boundary: exact row min via DPP, then threshold
      #pragma unroll
      for (int r = 0; r < 4; ++r) {
        m0[r] = FMIN_DPP(m0[r], 0xB1);  m0[r] = FMIN_DPP(m0[r], 0x4E);
        m0[r] = FMIN_DPP(m0[r], 0x141); m0[r] = FMIN_DPP(m0[r], 0x140);
        m1[r] = FMIN_DPP(m1[r], 0xB1);  m1[r] = FMIN_DPP(m1[r], 0x4E);
        m1[r] = FMIN_DPP(m1[r], 0x141); m1[r] = FMIN_DPP(m1[r], 0x140);
        thr0[r] = m0[r] + MARGIN;
        thr1[r] = m1[r] + MARGIN;
      }
    }
    __builtin_amdgcn_s_barrier();   // all waves done reading buf[cur]
    asm volatile("" ::: "memory");
  }

  // ---- publish the block's candidate list: ONE global atomic per block ----
  __syncthreads();
  int lc = lcount; if (lc > LCAP) lc = LCAP;
  if (tid == 0) gbase = atomicAdd(count, lc);
  __syncthreads();
  int gb = gbase;
  for (int i = tid; i < lc; i += 256) {
    int gp = gb + i;
    if (gp < CAP) list[gp] = cbuf[i];
  }
}

// ---------------- exact fp32 refine of candidates ---------------------------
__global__ __launch_bounds__(256) void refine_kernel(
    const float* __restrict__ Xrow, const float* __restrict__ E,
    const float* __restrict__ e2, const unsigned* __restrict__ list,
    const int* __restrict__ count, unsigned long long* __restrict__ rkey)
{
  const int lane = threadIdx.x & 63;
  const int wid = (blockIdx.x * 256 + threadIdx.x) >> 6;
  int cnt = *count; if (cnt > CAP) cnt = CAP;
  for (int i = wid; i < cnt; i += 4096) {
    unsigned p = list[i];
    int row = p >> 11, k = p & 2047;
    const float4 xv = reinterpret_cast<const float4*>(Xrow + (size_t)row * CDIM)[lane];
    const float4 ev = reinterpret_cast<const float4*>(E + (size_t)k * CDIM)[lane];
    float d = fmaf(xv.x, ev.x, fmaf(xv.y, ev.y, fmaf(xv.z, ev.z, xv.w * ev.w)));
    #pragma unroll
    for (int off = 32; off > 0; off >>= 1) d += __shfl_xor(d, off);
    if (lane == 0) {
      float s = fmaf(-2.f, d, e2[k]);
      unsigned u = __float_as_uint(s);
      u = (u & 0x80000000u) ? ~u : (u | 0x80000000u);   // monotone encode
      unsigned long long key = ((unsigned long long)u << 32) | (unsigned)k;
      atomicMin(&rkey[row], key);   // order-independent -> deterministic
    }
  }
}

// ---------------- gather codebook rows + MSE partials (reads rkey) ----------
__global__ __launch_bounds__(256) void out_kernel(
    const float* __restrict__ X, const float* __restrict__ E,
    const unsigned long long* __restrict__ rkey, float* __restrict__ out,
    float* __restrict__ partial)
{
  __shared__ float warpsum[4];
  size_t t = (size_t)blockIdx.x * 256 + threadIdx.x;
  size_t base = t * 8;
  float lsum = 0.f;
  #pragma unroll
  for (int g = 0; g < 2; ++g) {
    size_t e0 = base + (size_t)g * 4;
    int b = (int)(e0 >> 18);
    int c = (int)((e0 >> 10) & 255);
    int n = (int)(e0 & 1023);
    const unsigned long long* kp = rkey + b * HWN + n;
    int i0 = (int)(kp[0] & 2047ULL), i1 = (int)(kp[1] & 2047ULL);
    int i2 = (int)(kp[2] & 2047ULL), i3 = (int)(kp[3] & 2047ULL);
    float4 q;
    q.x = E[(size_t)i0 * CDIM + c];
    q.y = E[(size_t)i1 * CDIM + c];
    q.z = E[(size_t)i2 * CDIM + c];
    q.w = E[(size_t)i3 * CDIM + c];
    const float4 xv = *reinterpret_cast<const float4*>(X + e0);
    *reinterpret_cast<float4*>(out + e0) = q;
    float dx = xv.x - q.x, dy = xv.y - q.y, dz = xv.z - q.z, dw = xv.w - q.w;
    lsum += dx*dx + dy*dy + dz*dz + dw*dw;
  }
  #pragma unroll
  for (int off = 32; off > 0; off >>= 1) lsum += __shfl_down(lsum, off);
  int lane = threadIdx.x & 63, wv = threadIdx.x >> 6;
  if (lane == 0) warpsum[wv] = lsum;
  __syncthreads();
  if (threadIdx.x == 0)
    partial[blockIdx.x] = warpsum[0] + warpsum[1] + warpsum[2] + warpsum[3];
}

// ---------------- deterministic final loss reduce ---------------------------
__global__ __launch_bounds__(256) void loss_kernel(const float* __restrict__ partial,
                                                   float* __restrict__ out_loss) {
  __shared__ double sd[256];
  double s = 0.0;
  for (int i = threadIdx.x; i < 4096; i += 256) s += (double)partial[i];
  sd[threadIdx.x] = s;
  __syncthreads();
  if (threadIdx.x == 0) {
    double tot = 0.0;
    for (int i = 0; i < 256; ++i) tot += sd[i];
    out_loss[0] = (float)(tot / 8388608.0);
  }
}

extern "C" void kernel_launch(void* const* d_in, const int* in_sizes, int n_in,
                              void* d_out, int out_size, void* d_ws, size_t ws_size,
                              hipStream_t stream) {
  const float* X = (const float*)d_in[0];   // [32,256,32,32] fp32
  const float* E = (const float*)d_in[1];   // [2048,256] fp32
  float* out = (float*)d_out;               // 8388608 quantized + 1 loss
  char* ws = (char*)d_ws;

  float*              e2    = (float*)(ws + 0);                 // 8 KB
  unsigned short*     Ebf   = (unsigned short*)(ws + 8192);     // 1 MB
  unsigned short*     Xbf   = (unsigned short*)(ws + 1056768);  // 16 MB
  unsigned long long* rkey  = (unsigned long long*)(ws + 17833984); // 256 KB
  int*                count = (int*)(ws + 18096128);            // 256 B
  unsigned*           list  = (unsigned*)(ws + 18227456);       // 2 MB
  float*              partial = (float*)(ws + 20324608);        // 16 KB
  float* Xrow = out;   // fp32 row-major X stashed in d_out; overwritten by out_kernel

  prep_kernel  <<<2560, 256, 0, stream>>>(X, Xrow, Xbf, rkey, count, E, e2, Ebf);
  cand_kernel  <<<512,  256, 0, stream>>>(Xbf, Ebf, e2, list, count);
  refine_kernel<<<1024, 256, 0, stream>>>(Xrow, E, e2, list, count, rkey);
  out_kernel   <<<4096, 256, 0, stream>>>(X, E, rkey, out, partial);
  loss_kernel  <<<1,    256, 0, stream>>>(partial, out + 8388608);
}